// Round 16
// baseline (124.967 us; speedup 1.0000x reference)
//
#include <hip/hip_runtime.h>

// SimpleDHSRNN fused forward, round 16: r15 (M=8 real rows, grid 1024,
// 4 blocks/CU) with the s_sleep immediate-constant fix (switch on blockIdx&3).
// Numerics for real rows bit-identical to r12/r14.

typedef float    f32x4 __attribute__((ext_vector_type(4)));
typedef _Float16 f16x8 __attribute__((ext_vector_type(8)));

#define MFMA16F(a, b, c) __builtin_amdgcn_mfma_f32_16x16x32_f16((a), (b), (c), 0, 0, 0)
#define T_STEPS 196
#define S1S 40    // H1 row stride (f16 elems): 80 B
#define S2S 72    // H2 row stride (f16 elems): 144 B
#define H1B (16 * S1S)
#define H2B (16 * S2S)

// d_ws layout (floats) — all M/c entries pre-scaled by (1-alpha_branch)
#define WS_M1H 0        // [2][32][32]
#define WS_M1X 2048     // [2][32]
#define WS_C1  2112     // [2][32]
#define WS_M2  2176     // [2][64][96]
#define WS_C2  14464    // [2][64]
#define WS_TOTAL 14592

__global__ void prep_fuse(const float* __restrict__ r1_bw, const float* __restrict__ r1_bb,
                          const float* __restrict__ r1_ow, const float* __restrict__ r2_bw,
                          const float* __restrict__ r2_bb, const float* __restrict__ r2_ow,
                          float* __restrict__ ws)
{
    int idx = blockIdx.x * 256 + threadIdx.x;
    if (idx >= WS_TOTAL) return;
    float acc = 0.0f;
    float sc;
    if (idx < WS_M1X) {                     // M1h[kb][n][k]
        int kb = idx >> 10, rem = idx & 1023, n = rem >> 5, k = rem & 31;
        sc = kb ? 0.3f : 0.7f;
        for (int j = 0; j < 32; ++j)
            acc += r1_ow[n * 64 + kb * 32 + j] * r1_bw[(kb * 32 + j) * 33 + 1 + k];
    } else if (idx < WS_C1) {               // m1x[kb][n]
        int r = idx - WS_M1X; int kb = r >> 5, n = r & 31;
        sc = kb ? 0.3f : 0.7f;
        for (int j = 0; j < 32; ++j)
            acc += r1_ow[n * 64 + kb * 32 + j] * r1_bw[(kb * 32 + j) * 33];
    } else if (idx < WS_M2) {               // c1[kb][n]
        int r = idx - WS_C1; int kb = r >> 5, n = r & 31;
        sc = kb ? 0.3f : 0.7f;
        for (int j = 0; j < 32; ++j)
            acc += r1_ow[n * 64 + kb * 32 + j] * r1_bb[kb * 32 + j];
    } else if (idx < WS_C2) {               // M2[kb][n][k]
        int r = idx - WS_M2; int kb = r / 6144; int r2 = r - kb * 6144;
        int n = r2 / 96, k = r2 - n * 96;
        sc = kb ? 0.3f : 0.7f;
        for (int j = 0; j < 64; ++j)
            acc += r2_ow[n * 128 + kb * 64 + j] * r2_bw[(kb * 64 + j) * 96 + k];
    } else {                                // c2[kb][n]
        int r = idx - WS_C2; int kb = r >> 6, n = r & 63;
        sc = kb ? 0.3f : 0.7f;
        for (int j = 0; j < 64; ++j)
            acc += r2_ow[n * 128 + kb * 64 + j] * r2_bb[kb * 64 + j];
    }
    ws[idx] = acc * sc;
}

__device__ __forceinline__ f16x8 cvt8(const float* __restrict__ p) {
    f16x8 o;
#pragma unroll
    for (int i = 0; i < 8; ++i) o[i] = (_Float16)p[i];
    return o;
}

__global__ __launch_bounds__(256, 4)
void dhsrnn_f16(const float* __restrict__ x, const float* __restrict__ ws,
                const float* __restrict__ r1_ob, const float* __restrict__ r2_ob,
                const float* __restrict__ cw, const float* __restrict__ cb,
                float* __restrict__ out)
{
    __shared__ __align__(16) _Float16 H1[2 * H1B];
    __shared__ __align__(16) _Float16 H2[2 * H2B];
    __shared__ float XBuf[2][16];
    __shared__ float hcf[16 * 68];   // fp32 h2(T-1) for classifier

    const int tid = threadIdx.x;
    const int w   = tid >> 6;
    const int l   = tid & 63;
    const int li  = l & 15;
    const int g   = l >> 4;
    const int row0 = blockIdx.x * 8;          // 8 REAL rows per block

    // ---- L2 weights (all waves): N=64, K=96 ----
    const int n4 = w * 16 + li;
    f16x8 B2a[3], B2b[3];
#pragma unroll
    for (int kt = 0; kt < 3; ++kt) {
        B2a[kt] = cvt8(ws + WS_M2 + 0 * 6144 + n4 * 96 + kt * 32 + g * 8);
        B2b[kt] = cvt8(ws + WS_M2 + 1 * 6144 + n4 * 96 + kt * 32 + g * 8);
    }
    const float c2a = ws[WS_C2 + n4], c2b = ws[WS_C2 + 64 + n4];
    const float ob2n = r2_ob[n4];
    const f32x4 ci2a = {c2a, c2a, c2a, c2a};
    const f32x4 ci2b = {c2b, c2b, c2b, c2b};

    // ---- L1 weights (waves 2,3): N=32, K=32 ----
    const int n2 = (w & 1) * 16 + li;
    f16x8 B1a, B1b;
    float m1xa = 0.f, m1xb = 0.f, c1a = 0.f, c1b = 0.f, ob1n = 0.f;
    if (w >= 2) {
        B1a = cvt8(ws + WS_M1H + 0 * 1024 + n2 * 32 + g * 8);
        B1b = cvt8(ws + WS_M1H + 1 * 1024 + n2 * 32 + g * 8);
        m1xa = ws[WS_M1X + n2];      m1xb = ws[WS_M1X + 32 + n2];
        c1a  = ws[WS_C1 + n2];       c1b  = ws[WS_C1 + 32 + n2];
        ob1n = r1_ob[n2];
    }
    const f32x4 ci1a = {c1a, c1a, c1a, c1a};
    const f32x4 ci1b = {c1b, c1b, c1b, c1b};

    // EMA states (fp32, acc layout m = 4g + r)
    f32x4 va  = {0.f, 0.f, 0.f, 0.f}, vb  = {0.f, 0.f, 0.f, 0.f};
    f32x4 va2 = {0.f, 0.f, 0.f, 0.f}, vb2 = {0.f, 0.f, 0.f, 0.f};

    // ---- init (x rows clamped in-bounds; padded rows get finite data) ----
    for (int i = tid; i < H2B; i += 256) H2[i] = (_Float16)0.0f;
    if (tid < 16) {
        int xr = min(row0 + tid, 8191);
        XBuf[0][tid] = x[xr * 784];
        XBuf[1][tid] = x[xr * 784 + 4];
    }
    __syncthreads();

    // ---- prologue: h1(0) ----
    if (w >= 2) {
        const f32x4 xv = *reinterpret_cast<const f32x4*>(&XBuf[0][4 * g]);
#pragma unroll
        for (int r = 0; r < 4; ++r) {
            int m = 4 * g + r;
            va[r] = c1a + m1xa * xv[r];
            vb[r] = c1b + m1xb * xv[r];
            float h = fmaxf(va[r] + vb[r] + ob1n, 0.0f);
            H1[m * S1S + n2] = (_Float16)h;
        }
    }
    __syncthreads();

    // ---- phase stagger: constant-immediate sleeps per co-resident slot ----
    switch (blockIdx.x & 3) {
        case 1: __builtin_amdgcn_s_sleep(4);  break;   // ~256 cyc
        case 2: __builtin_amdgcn_s_sleep(8);  break;   // ~512 cyc
        case 3: __builtin_amdgcn_s_sleep(12); break;   // ~768 cyc
        default: break;
    }

    // one step, rb/wb compile-time after inlining; no hcf path in hot body
    auto step = [&](const int rb, const int t) {
        const int wb = rb ^ 1;

        float xnext = 0.0f;
        if (w == 1 && l < 16 && t < T_STEPS - 2)
            xnext = x[min(row0 + l, 8191) * 784 + 4 * (t + 2)];

        const f16x8 a1   = *reinterpret_cast<const f16x8*>(&H1[rb * H1B + li * S1S + g * 8]);
        const f16x8 a2k1 = *reinterpret_cast<const f16x8*>(&H2[rb * H2B + li * S2S + g * 8]);
        const f16x8 a2k2 = *reinterpret_cast<const f16x8*>(&H2[rb * H2B + li * S2S + 32 + g * 8]);

        // L2(t): bias rides in as the C operand of the first MFMA
        __builtin_amdgcn_s_setprio(1);
        f32x4 d = MFMA16F(a1, B2a[0], ci2a);
        f32x4 e = MFMA16F(a1, B2b[0], ci2b);
        d = MFMA16F(a2k1, B2a[1], d);
        e = MFMA16F(a2k1, B2b[1], e);
        d = MFMA16F(a2k2, B2a[2], d);
        e = MFMA16F(a2k2, B2b[2], e);
        __builtin_amdgcn_s_setprio(0);
#pragma unroll
        for (int r = 0; r < 4; ++r) {
            int m = 4 * g + r;
            va2[r] = fmaf(0.3f, va2[r], d[r]);
            vb2[r] = fmaf(0.7f, vb2[r], e[r]);
            float h = fmaxf(va2[r] + vb2[r] + ob2n, 0.0f);
            H2[wb * H2B + m * S2S + n4] = (_Float16)h;
        }

        // L1(t+1): waves 2,3 (reuse a1)
        if (w >= 2) {
            __builtin_amdgcn_s_setprio(1);
            f32x4 p = MFMA16F(a1, B1a, ci1a);
            f32x4 q = MFMA16F(a1, B1b, ci1b);
            __builtin_amdgcn_s_setprio(0);
            const f32x4 xv = *reinterpret_cast<const f32x4*>(&XBuf[wb][4 * g]);
#pragma unroll
            for (int r = 0; r < 4; ++r) {
                int m = 4 * g + r;
                float za = fmaf(m1xa, xv[r], p[r]);
                float zb = fmaf(m1xb, xv[r], q[r]);
                va[r] = fmaf(0.3f, va[r], za);
                vb[r] = fmaf(0.7f, vb[r], zb);
                float h = fmaxf(va[r] + vb[r] + ob1n, 0.0f);
                H1[wb * H1B + m * S1S + n2] = (_Float16)h;
            }
        }

        if (w == 1 && l < 16 && t < T_STEPS - 2) XBuf[rb][l] = xnext;
        __syncthreads();
    };

    // ---- hot loop: t = 0..193 in unrolled pairs, then t = 194 ----
#pragma unroll 1
    for (int tp = 0; tp < (T_STEPS - 2) / 2; ++tp) {
        step(0, 2 * tp);
        step(1, 2 * tp + 1);
    }
    step(0, T_STEPS - 2);   // t=194 (rb=0): computes h2(194), h1(195)

    // ---- peeled final step t=195 (rb=1): h2(195) -> hcf only ----
    {
        const int rb = 1;
        const f16x8 a1   = *reinterpret_cast<const f16x8*>(&H1[rb * H1B + li * S1S + g * 8]);
        const f16x8 a2k1 = *reinterpret_cast<const f16x8*>(&H2[rb * H2B + li * S2S + g * 8]);
        const f16x8 a2k2 = *reinterpret_cast<const f16x8*>(&H2[rb * H2B + li * S2S + 32 + g * 8]);
        f32x4 d = MFMA16F(a1, B2a[0], ci2a);
        f32x4 e = MFMA16F(a1, B2b[0], ci2b);
        d = MFMA16F(a2k1, B2a[1], d);
        e = MFMA16F(a2k1, B2b[1], e);
        d = MFMA16F(a2k2, B2a[2], d);
        e = MFMA16F(a2k2, B2b[2], e);
#pragma unroll
        for (int r = 0; r < 4; ++r) {
            int m = 4 * g + r;
            va2[r] = fmaf(0.3f, va2[r], d[r]);
            vb2[r] = fmaf(0.7f, vb2[r], e[r]);
            hcf[m * 68 + n4] = fmaxf(va2[r] + vb2[r] + ob2n, 0.0f);
        }
    }
    __syncthreads();

    // ---- classifier: only the 8 real rows ----
    {
        const int c = tid >> 4;
        const int e = tid & 15;
        if (c < 10 && e < 8) {
            float acc = cb[c];
#pragma unroll 4
            for (int dd = 0; dd < 64; ++dd)
                acc += hcf[e * 68 + dd] * cw[c * 64 + dd];
            out[(row0 + e) * 10 + c] = acc;
        }
    }
}

extern "C" void kernel_launch(void* const* d_in, const int* in_sizes, int n_in,
                              void* d_out, int out_size, void* d_ws, size_t ws_size,
                              hipStream_t stream) {
    const float* x     = (const float*)d_in[0];
    const float* r1_bw = (const float*)d_in[1];
    const float* r1_bb = (const float*)d_in[2];
    const float* r1_ow = (const float*)d_in[3];
    const float* r1_ob = (const float*)d_in[4];
    const float* r2_bw = (const float*)d_in[5];
    const float* r2_bb = (const float*)d_in[6];
    const float* r2_ow = (const float*)d_in[7];
    const float* r2_ob = (const float*)d_in[8];
    const float* cw    = (const float*)d_in[9];
    const float* cb    = (const float*)d_in[10];
    float* ws  = (float*)d_ws;
    float* out = (float*)d_out;

    hipLaunchKernelGGL(prep_fuse, dim3((WS_TOTAL + 255) / 256), dim3(256), 0, stream,
                       r1_bw, r1_bb, r1_ow, r2_bw, r2_bb, r2_ow, ws);
    hipLaunchKernelGGL(dhsrnn_f16, dim3(1024), dim3(256), 0, stream,
                       x, ws, r1_ob, r2_ob, cw, cb, out);
}

// Round 17
// 88.213 us; speedup vs baseline: 1.4167x; 1.4167x over previous
//
#include <hip/hip_runtime.h>

// SimpleDHSRNN fused forward — FINAL (round 14 config, best measured: 88.5 us).
// Techniques accumulated: all-in-LDS weights -> register-resident fused weights;
// algebraic cell fusion (v = Wo·s EMA recurrence, M = (1-a)Wo·Wb precomputed);
// cross-layer software pipeline (L2(t) ∥ L1(t+1), one barrier/step);
// single-plane f16 numerics (fp32 EMA states in registers); 2-step unroll;
// peeled final step; setprio around MFMA clusters.
// Block = 256 thr = 4 waves, M=16 rows, grid = 512 (2 blocks/CU).

typedef float    f32x4 __attribute__((ext_vector_type(4)));
typedef _Float16 f16x8 __attribute__((ext_vector_type(8)));

#define MFMA16F(a, b, c) __builtin_amdgcn_mfma_f32_16x16x32_f16((a), (b), (c), 0, 0, 0)
#define T_STEPS 196
#define S1S 40    // H1 row stride (f16 elems): 80 B
#define S2S 72    // H2 row stride (f16 elems): 144 B
#define H1B (16 * S1S)
#define H2B (16 * S2S)

// d_ws layout (floats) — all M/c entries pre-scaled by (1-alpha_branch)
#define WS_M1H 0        // [2][32][32]
#define WS_M1X 2048     // [2][32]
#define WS_C1  2112     // [2][32]
#define WS_M2  2176     // [2][64][96]
#define WS_C2  14464    // [2][64]
#define WS_TOTAL 14592

__global__ void prep_fuse(const float* __restrict__ r1_bw, const float* __restrict__ r1_bb,
                          const float* __restrict__ r1_ow, const float* __restrict__ r2_bw,
                          const float* __restrict__ r2_bb, const float* __restrict__ r2_ow,
                          float* __restrict__ ws)
{
    int idx = blockIdx.x * 256 + threadIdx.x;
    if (idx >= WS_TOTAL) return;
    float acc = 0.0f;
    float sc;
    if (idx < WS_M1X) {                     // M1h[kb][n][k]
        int kb = idx >> 10, rem = idx & 1023, n = rem >> 5, k = rem & 31;
        sc = kb ? 0.3f : 0.7f;
        for (int j = 0; j < 32; ++j)
            acc += r1_ow[n * 64 + kb * 32 + j] * r1_bw[(kb * 32 + j) * 33 + 1 + k];
    } else if (idx < WS_C1) {               // m1x[kb][n]
        int r = idx - WS_M1X; int kb = r >> 5, n = r & 31;
        sc = kb ? 0.3f : 0.7f;
        for (int j = 0; j < 32; ++j)
            acc += r1_ow[n * 64 + kb * 32 + j] * r1_bw[(kb * 32 + j) * 33];
    } else if (idx < WS_M2) {               // c1[kb][n]
        int r = idx - WS_C1; int kb = r >> 5, n = r & 31;
        sc = kb ? 0.3f : 0.7f;
        for (int j = 0; j < 32; ++j)
            acc += r1_ow[n * 64 + kb * 32 + j] * r1_bb[kb * 32 + j];
    } else if (idx < WS_C2) {               // M2[kb][n][k]
        int r = idx - WS_M2; int kb = r / 6144; int r2 = r - kb * 6144;
        int n = r2 / 96, k = r2 - n * 96;
        sc = kb ? 0.3f : 0.7f;
        for (int j = 0; j < 64; ++j)
            acc += r2_ow[n * 128 + kb * 64 + j] * r2_bw[(kb * 64 + j) * 96 + k];
    } else {                                // c2[kb][n]
        int r = idx - WS_C2; int kb = r >> 6, n = r & 63;
        sc = kb ? 0.3f : 0.7f;
        for (int j = 0; j < 64; ++j)
            acc += r2_ow[n * 128 + kb * 64 + j] * r2_bb[kb * 64 + j];
    }
    ws[idx] = acc * sc;
}

__device__ __forceinline__ f16x8 cvt8(const float* __restrict__ p) {
    f16x8 o;
#pragma unroll
    for (int i = 0; i < 8; ++i) o[i] = (_Float16)p[i];
    return o;
}

__global__ __launch_bounds__(256, 2)
void dhsrnn_f16(const float* __restrict__ x, const float* __restrict__ ws,
                const float* __restrict__ r1_ob, const float* __restrict__ r2_ob,
                const float* __restrict__ cw, const float* __restrict__ cb,
                float* __restrict__ out)
{
    __shared__ __align__(16) _Float16 H1[2 * H1B];
    __shared__ __align__(16) _Float16 H2[2 * H2B];
    __shared__ float XBuf[2][16];
    __shared__ float hcf[16 * 68];   // fp32 h2(T-1) for classifier

    const int tid = threadIdx.x;
    const int w   = tid >> 6;
    const int l   = tid & 63;
    const int li  = l & 15;
    const int g   = l >> 4;
    const int row0 = blockIdx.x * 16;

    // ---- L2 weights (all waves): N=64, K=96 ----
    const int n4 = w * 16 + li;
    f16x8 B2a[3], B2b[3];
#pragma unroll
    for (int kt = 0; kt < 3; ++kt) {
        B2a[kt] = cvt8(ws + WS_M2 + 0 * 6144 + n4 * 96 + kt * 32 + g * 8);
        B2b[kt] = cvt8(ws + WS_M2 + 1 * 6144 + n4 * 96 + kt * 32 + g * 8);
    }
    const float c2a = ws[WS_C2 + n4], c2b = ws[WS_C2 + 64 + n4];
    const float ob2n = r2_ob[n4];
    const f32x4 ci2a = {c2a, c2a, c2a, c2a};
    const f32x4 ci2b = {c2b, c2b, c2b, c2b};

    // ---- L1 weights (waves 2,3): N=32, K=32 ----
    const int n2 = (w & 1) * 16 + li;
    f16x8 B1a, B1b;
    float m1xa = 0.f, m1xb = 0.f, c1a = 0.f, c1b = 0.f, ob1n = 0.f;
    if (w >= 2) {
        B1a = cvt8(ws + WS_M1H + 0 * 1024 + n2 * 32 + g * 8);
        B1b = cvt8(ws + WS_M1H + 1 * 1024 + n2 * 32 + g * 8);
        m1xa = ws[WS_M1X + n2];      m1xb = ws[WS_M1X + 32 + n2];
        c1a  = ws[WS_C1 + n2];       c1b  = ws[WS_C1 + 32 + n2];
        ob1n = r1_ob[n2];
    }
    const f32x4 ci1a = {c1a, c1a, c1a, c1a};
    const f32x4 ci1b = {c1b, c1b, c1b, c1b};

    // EMA states (fp32, acc layout m = 4g + r)
    f32x4 va  = {0.f, 0.f, 0.f, 0.f}, vb  = {0.f, 0.f, 0.f, 0.f};
    f32x4 va2 = {0.f, 0.f, 0.f, 0.f}, vb2 = {0.f, 0.f, 0.f, 0.f};

    // ---- init ----
    for (int i = tid; i < H2B; i += 256) H2[i] = (_Float16)0.0f;
    if (tid < 16) {
        XBuf[0][tid] = x[(row0 + tid) * 784];
        XBuf[1][tid] = x[(row0 + tid) * 784 + 4];
    }
    __syncthreads();

    // ---- prologue: h1(0) ----
    if (w >= 2) {
        const f32x4 xv = *reinterpret_cast<const f32x4*>(&XBuf[0][4 * g]);
#pragma unroll
        for (int r = 0; r < 4; ++r) {
            int m = 4 * g + r;
            va[r] = c1a + m1xa * xv[r];
            vb[r] = c1b + m1xb * xv[r];
            float h = fmaxf(va[r] + vb[r] + ob1n, 0.0f);
            H1[m * S1S + n2] = (_Float16)h;
        }
    }
    __syncthreads();

    // ---- phase stagger (neutral in A/B; harmless) ----
    if (blockIdx.x & 1) __builtin_amdgcn_s_sleep(8);

    // one step, rb/wb compile-time after inlining; no hcf path in hot body
    auto step = [&](const int rb, const int t) {
        const int wb = rb ^ 1;

        float xnext = 0.0f;
        if (w == 1 && l < 16 && t < T_STEPS - 2)
            xnext = x[(row0 + l) * 784 + 4 * (t + 2)];

        const f16x8 a1   = *reinterpret_cast<const f16x8*>(&H1[rb * H1B + li * S1S + g * 8]);
        const f16x8 a2k1 = *reinterpret_cast<const f16x8*>(&H2[rb * H2B + li * S2S + g * 8]);
        const f16x8 a2k2 = *reinterpret_cast<const f16x8*>(&H2[rb * H2B + li * S2S + 32 + g * 8]);

        // L2(t): bias rides in as the C operand of the first MFMA
        __builtin_amdgcn_s_setprio(1);
        f32x4 d = MFMA16F(a1, B2a[0], ci2a);
        f32x4 e = MFMA16F(a1, B2b[0], ci2b);
        d = MFMA16F(a2k1, B2a[1], d);
        e = MFMA16F(a2k1, B2b[1], e);
        d = MFMA16F(a2k2, B2a[2], d);
        e = MFMA16F(a2k2, B2b[2], e);
        __builtin_amdgcn_s_setprio(0);
#pragma unroll
        for (int r = 0; r < 4; ++r) {
            int m = 4 * g + r;
            va2[r] = fmaf(0.3f, va2[r], d[r]);
            vb2[r] = fmaf(0.7f, vb2[r], e[r]);
            float h = fmaxf(va2[r] + vb2[r] + ob2n, 0.0f);
            H2[wb * H2B + m * S2S + n4] = (_Float16)h;
        }

        // L1(t+1): waves 2,3 (reuse a1)
        if (w >= 2) {
            __builtin_amdgcn_s_setprio(1);
            f32x4 p = MFMA16F(a1, B1a, ci1a);
            f32x4 q = MFMA16F(a1, B1b, ci1b);
            __builtin_amdgcn_s_setprio(0);
            const f32x4 xv = *reinterpret_cast<const f32x4*>(&XBuf[wb][4 * g]);
#pragma unroll
            for (int r = 0; r < 4; ++r) {
                int m = 4 * g + r;
                float za = fmaf(m1xa, xv[r], p[r]);
                float zb = fmaf(m1xb, xv[r], q[r]);
                va[r] = fmaf(0.3f, va[r], za);
                vb[r] = fmaf(0.7f, vb[r], zb);
                float h = fmaxf(va[r] + vb[r] + ob1n, 0.0f);
                H1[wb * H1B + m * S1S + n2] = (_Float16)h;
            }
        }

        if (w == 1 && l < 16 && t < T_STEPS - 2) XBuf[rb][l] = xnext;
        __syncthreads();
    };

    // ---- hot loop: t = 0..193 in unrolled pairs, then t = 194 ----
#pragma unroll 1
    for (int tp = 0; tp < (T_STEPS - 2) / 2; ++tp) {
        step(0, 2 * tp);
        step(1, 2 * tp + 1);
    }
    step(0, T_STEPS - 2);   // t=194 (rb=0): computes h2(194), h1(195)

    // ---- peeled final step t=195 (rb=1): h2(195) -> hcf only ----
    {
        const int rb = 1;
        const f16x8 a1   = *reinterpret_cast<const f16x8*>(&H1[rb * H1B + li * S1S + g * 8]);
        const f16x8 a2k1 = *reinterpret_cast<const f16x8*>(&H2[rb * H2B + li * S2S + g * 8]);
        const f16x8 a2k2 = *reinterpret_cast<const f16x8*>(&H2[rb * H2B + li * S2S + 32 + g * 8]);
        f32x4 d = MFMA16F(a1, B2a[0], ci2a);
        f32x4 e = MFMA16F(a1, B2b[0], ci2b);
        d = MFMA16F(a2k1, B2a[1], d);
        e = MFMA16F(a2k1, B2b[1], e);
        d = MFMA16F(a2k2, B2a[2], d);
        e = MFMA16F(a2k2, B2b[2], e);
#pragma unroll
        for (int r = 0; r < 4; ++r) {
            int m = 4 * g + r;
            va2[r] = fmaf(0.3f, va2[r], d[r]);
            vb2[r] = fmaf(0.7f, vb2[r], e[r]);
            hcf[m * 68 + n4] = fmaxf(va2[r] + vb2[r] + ob2n, 0.0f);
        }
    }
    __syncthreads();

    // ---- classifier ----
    {
        const int c = tid >> 4;
        const int e = tid & 15;
        if (c < 10) {
            float acc = cb[c];
#pragma unroll 4
            for (int dd = 0; dd < 64; ++dd)
                acc += hcf[e * 68 + dd] * cw[c * 64 + dd];
            out[(row0 + e) * 10 + c] = acc;
        }
    }
}

extern "C" void kernel_launch(void* const* d_in, const int* in_sizes, int n_in,
                              void* d_out, int out_size, void* d_ws, size_t ws_size,
                              hipStream_t stream) {
    const float* x     = (const float*)d_in[0];
    const float* r1_bw = (const float*)d_in[1];
    const float* r1_bb = (const float*)d_in[2];
    const float* r1_ow = (const float*)d_in[3];
    const float* r1_ob = (const float*)d_in[4];
    const float* r2_bw = (const float*)d_in[5];
    const float* r2_bb = (const float*)d_in[6];
    const float* r2_ow = (const float*)d_in[7];
    const float* r2_ob = (const float*)d_in[8];
    const float* cw    = (const float*)d_in[9];
    const float* cb    = (const float*)d_in[10];
    float* ws  = (float*)d_ws;
    float* out = (float*)d_out;

    hipLaunchKernelGGL(prep_fuse, dim3((WS_TOTAL + 255) / 256), dim3(256), 0, stream,
                       r1_bw, r1_bb, r1_ow, r2_bw, r2_bb, r2_ow, ws);
    hipLaunchKernelGGL(dhsrnn_f16, dim3(512), dim3(256), 0, stream,
                       x, ws, r1_ob, r2_ob, cw, cb, out);
}